// Round 9
// baseline (613.618 us; speedup 1.0000x reference)
//
#include <hip/hip_runtime.h>

typedef unsigned short u16;
typedef __attribute__((ext_vector_type(8))) short short8;
typedef __attribute__((ext_vector_type(4))) float floatx4;

#define B_ 128
#define S_ 500
#define FCIN 16000
#define HID 1024
#define QSCL 0.72134752044448169f   // 0.5 * log2(e)

#if __has_builtin(__builtin_amdgcn_exp2f)
#define EXP2(x) __builtin_amdgcn_exp2f(x)
#else
#define EXP2(x) exp2f(x)
#endif

__device__ __forceinline__ float bf2f(u16 u) {
    union { unsigned u32; float f; } x;
    x.u32 = ((unsigned)u) << 16;
    return x.f;
}
__device__ __forceinline__ u16 f2bf(float f) {           // RNE (epilogues)
    union { float f; unsigned u; } x;
    x.f = f;
    unsigned u = x.u;
    return (u16)((u + 0x7fff + ((u >> 16) & 1)) >> 16);
}
__device__ __forceinline__ u16 bfhu(float f) {           // half-up, 2 ops
    union { float f; unsigned u; } x;
    x.f = f;
    return (u16)((x.u + 0x8000u) >> 16);
}
__device__ __forceinline__ unsigned pkbf2(float a, float b) { // pack 2 bf16
    union { float f; unsigned u; } x, y;
    x.f = a; y.f = b;
    return ((x.u + 0x8000u) >> 16) | ((y.u + 0x8000u) & 0xffff0000u);
}

// ---------------------------------------------------------------------------
// K1: fused QKV + MFMA attention. Block = (b,h), 256 thr / 4 waves.
// Phase 1 (fp32 VALU): one thread = one s-row; q,k hi/lo split-bf16 [512][8]
// in LDS (rows >= 500 zero); v as bf16 V^T [4][520] (cols >= 500 zero).
// Phase 2: exact scores via 2 chained MFMAs ([kh|kl]x[qh|ql] + [kl|kh]x..);
// raw exp2; P half-up bf16 staged per-wave in LDS; PV = mfma(A=V^T, B=P^T);
// rowsum in regs + 2 shfl_xor (pad keys corrected by -4 on kq>0 lanes).
// __launch_bounds__(256,4): cap 128 VGPR -> 4 waves/SIMD.
// ---------------------------------------------------------------------------
__global__ __launch_bounds__(256, 4) void attn_fused_mfma(
    const float* __restrict__ x,
    const float* __restrict__ Wq, const float* __restrict__ bq,
    const float* __restrict__ Wk, const float* __restrict__ bk,
    const float* __restrict__ Wv, const float* __restrict__ bv,
    u16* __restrict__ avbf)
{
    __shared__ float sWb[12 * 32];   // rows 0-3 Wq, 4-7 Wk, 8-11 Wv (head h)
    __shared__ float sBb[12];
    __shared__ u16 sQ8[512 * 8];     // [q][qh0..3, ql0..3]
    __shared__ u16 sK8[512 * 8];     // [key][kh0..3, kl0..3]
    __shared__ u16 sVT[4 * 520];     // [vcol][key]
    __shared__ u16 sP[4][640];       // per-wave P tile [q16][40]

    int tid = threadIdx.x;
    int bh = blockIdx.x, b = bh >> 3, h = bh & 7;

    for (int i = tid; i < 384; i += 256) {
        int r = i >> 5, d = i & 31;
        const float* src = (r < 4) ? (Wq + (h * 4 + r) * 32)
                         : (r < 8) ? (Wk + (h * 4 + r - 4) * 32)
                                   : (Wv + (h * 4 + r - 8) * 32);
        sWb[r * 32 + d] = src[d];
    }
    if (tid < 12)
        sBb[tid] = (tid < 4) ? bq[h * 4 + tid]
                 : (tid < 8) ? bk[h * 4 + tid - 4] : bv[h * 4 + tid - 8];
    __syncthreads();

    for (int s = tid; s < 512; s += 256) {
        bool valid = (s < S_);
        const float* xr = x + ((size_t)b * S_ + (valid ? s : 0)) * 32;
        float4 xv[8];
#pragma unroll
        for (int cc = 0; cc < 8; ++cc) xv[cc] = *(const float4*)(xr + cc * 4);
        float o[12];
#pragma unroll
        for (int r = 0; r < 12; ++r) {
            float acc = sBb[r];
            const float4* w4 = (const float4*)(sWb + r * 32);
#pragma unroll
            for (int cc = 0; cc < 8; ++cc) {
                float4 w = w4[cc];
                acc += xv[cc].x * w.x + xv[cc].y * w.y
                     + xv[cc].z * w.z + xv[cc].w * w.w;
            }
            o[r] = valid ? acc : 0.f;
        }
        short8 qrow, krow;
#pragma unroll
        for (int j = 0; j < 4; ++j) {
            float vq = o[j] * QSCL;
            u16 qh = bfhu(vq);
            qrow[j] = (short)qh; qrow[4 + j] = (short)bfhu(vq - bf2f(qh));
            float vk = o[4 + j];
            u16 kh = bfhu(vk);
            krow[j] = (short)kh; krow[4 + j] = (short)bfhu(vk - bf2f(kh));
            sVT[j * 520 + s] = bfhu(o[8 + j]);
        }
        *(short8*)(sQ8 + s * 8) = qrow;
        *(short8*)(sK8 + s * 8) = krow;
    }
    __syncthreads();

    int wid = tid >> 6, lane = tid & 63;
    int ln = lane & 15, kq = lane >> 4;
    u16* myP = sP[wid];
    const short8 z8 = {0, 0, 0, 0, 0, 0, 0, 0};
    floatx4 zero = {0.f, 0.f, 0.f, 0.f};

    for (int i = 0; i < 8; ++i) {
        int qt = wid + 4 * i;                        // q-tile [0,32)
        short8 qf = z8;
        if (kq == 0) qf = *(const short8*)(sQ8 + (qt * 16 + ln) * 8);

        floatx4 acc = zero;
        float rs = 0.f;

        for (int c = 0; c < 16; ++c) {
            short8 ka = z8, kb = z8;
            if (kq == 0) {
                ka = *(const short8*)(sK8 + ((2 * c) * 16 + ln) * 8);
                kb = *(const short8*)(sK8 + ((2 * c + 1) * 16 + ln) * 8);
            }
            short8 kas, kbs;
            kas[0] = ka[4]; kas[1] = ka[5]; kas[2] = ka[6]; kas[3] = ka[7];
            kas[4] = ka[0]; kas[5] = ka[1]; kas[6] = ka[2]; kas[7] = ka[3];
            kbs[0] = kb[4]; kbs[1] = kb[5]; kbs[2] = kb[6]; kbs[3] = kb[7];
            kbs[4] = kb[0]; kbs[5] = kb[1]; kbs[6] = kb[2]; kbs[7] = kb[3];

            floatx4 s1 = __builtin_amdgcn_mfma_f32_16x16x32_bf16(ka, qf, zero, 0, 0, 0);
            s1 = __builtin_amdgcn_mfma_f32_16x16x32_bf16(kas, qf, s1, 0, 0, 0);
            floatx4 s2 = __builtin_amdgcn_mfma_f32_16x16x32_bf16(kb, qf, zero, 0, 0, 0);
            s2 = __builtin_amdgcn_mfma_f32_16x16x32_bf16(kbs, qf, s2, 0, 0, 0);

            // C layout: col=ln=q, row=kq*4+r = local key
            float e10 = EXP2(s1[0]), e11 = EXP2(s1[1]),
                  e12 = EXP2(s1[2]), e13 = EXP2(s1[3]);
            float e20 = EXP2(s2[0]), e21 = EXP2(s2[1]),
                  e22 = EXP2(s2[2]), e23 = EXP2(s2[3]);

            rs += (e10 + e11) + (e12 + e13) + (e20 + e21) + (e22 + e23);

            uint2 w1, w2;
            w1.x = pkbf2(e10, e11); w1.y = pkbf2(e12, e13);
            w2.x = pkbf2(e20, e21); w2.y = pkbf2(e22, e23);
            *(uint2*)(myP + ln * 40 + kq * 4)      = w1;   // local keys 0-15
            *(uint2*)(myP + ln * 40 + 16 + kq * 4) = w2;   // local keys 16-31

            short8 pf = *(const short8*)(myP + ln * 40 + kq * 8);
            short8 vf = z8;
            if (ln < 4)
                vf = *(const short8*)(sVT + ln * 520 + c * 32 + kq * 8);
            acc = __builtin_amdgcn_mfma_f32_16x16x32_bf16(vf, pf, acc, 0, 0, 0);
        }

        if (kq > 0) rs -= 4.0f;      // pad keys 500-511: exp2(0)=1, 4/lane
        rs += __shfl_xor(rs, 16, 64);
        rs += __shfl_xor(rs, 32, 64);

        int q = qt * 16 + ln;
        if (kq == 0 && q < S_) {                     // D rows 0-3 = vcols
            float inv = 1.0f / rs;
            uint2 pk;
            pk.x = (unsigned)f2bf(acc[0] * inv) | ((unsigned)f2bf(acc[1] * inv) << 16);
            pk.y = (unsigned)f2bf(acc[2] * inv) | ((unsigned)f2bf(acc[3] * inv) << 16);
            *(uint2*)(avbf + ((size_t)(b * S_ + q) * 32 + h * 4)) = pk;
        }
    }
}

// ---------------------------------------------------------------------------
// K2: output projection via MFMA: flat = av @ Wo^T + bo (bf16 out).
// Also inits hidden[m][j] = b1[j] for fc1's atomic accumulation.
// ---------------------------------------------------------------------------
__global__ __launch_bounds__(256) void proj_mfma(
    const u16* __restrict__ avbf, const float* __restrict__ Wo,
    const float* __restrict__ bo, const float* __restrict__ b1,
    u16* __restrict__ flat, float* __restrict__ hidden)
{
    int tid = threadIdx.x;
    int gid = blockIdx.x * 256 + tid;
    if (gid < B_ * HID) hidden[gid] = b1[gid & (HID - 1)];

    int wid = tid >> 6, lane = tid & 63;
    int lm = lane & 15, kq = lane >> 4;
    int m0 = (blockIdx.x * 4 + wid) * 16;

    short8 af = *(const short8*)(avbf + (size_t)(m0 + lm) * 32 + kq * 8);
    floatx4 zero = {0.f, 0.f, 0.f, 0.f};
#pragma unroll
    for (int t2 = 0; t2 < 2; ++t2) {
        int d = t2 * 16 + lm;
        const float* wr = Wo + d * 32 + kq * 8;
        float4 w0 = *(const float4*)(wr);
        float4 w1 = *(const float4*)(wr + 4);
        short8 bf;
        bf[0] = (short)f2bf(w0.x); bf[1] = (short)f2bf(w0.y);
        bf[2] = (short)f2bf(w0.z); bf[3] = (short)f2bf(w0.w);
        bf[4] = (short)f2bf(w1.x); bf[5] = (short)f2bf(w1.y);
        bf[6] = (short)f2bf(w1.z); bf[7] = (short)f2bf(w1.w);
        floatx4 acc = __builtin_amdgcn_mfma_f32_16x16x32_bf16(af, bf, zero, 0, 0, 0);
        float bias = bo[d];
#pragma unroll
        for (int r = 0; r < 4; ++r) {
            int row = m0 + kq * 4 + r;
            flat[(size_t)row * 32 + d] = f2bf(acc[r] + bias);
        }
    }
}

// ---------------------------------------------------------------------------
// K3: FC1 via MFMA split-K (25 k-chunks x 16 n-groups = 400 blocks).
// ---------------------------------------------------------------------------
__global__ __launch_bounds__(256) void fc1_mfma(
    const u16* __restrict__ flatbf, const float* __restrict__ W1,
    float* __restrict__ hidden)
{
    int tid = threadIdx.x;
    int wid = tid >> 6, lane = tid & 63;
    int lm = lane & 15, kq = lane >> 4;
    int ng = blockIdx.x & 15, kc = blockIdx.x >> 4;   // kc in [0,25)
    int n0 = ng * 64 + wid * 16;

    floatx4 acc[8];
#pragma unroll
    for (int mt = 0; mt < 8; ++mt) acc[mt] = (floatx4){0.f, 0.f, 0.f, 0.f};

    const float* wrow = W1 + (size_t)(n0 + lm) * FCIN;
    const u16*  abase = flatbf + lm * FCIN;

    for (int step = 0; step < 20; ++step) {
        int kk = kc * 640 + step * 32 + kq * 8;
        float4 w0 = *(const float4*)(wrow + kk);
        float4 w1 = *(const float4*)(wrow + kk + 4);
        short8 bfr;
        bfr[0] = (short)f2bf(w0.x); bfr[1] = (short)f2bf(w0.y);
        bfr[2] = (short)f2bf(w0.z); bfr[3] = (short)f2bf(w0.w);
        bfr[4] = (short)f2bf(w1.x); bfr[5] = (short)f2bf(w1.y);
        bfr[6] = (short)f2bf(w1.z); bfr[7] = (short)f2bf(w1.w);
#pragma unroll
        for (int mt = 0; mt < 8; ++mt) {
            short8 afr = *(const short8*)(abase + mt * 16 * FCIN + kk);
            acc[mt] = __builtin_amdgcn_mfma_f32_16x16x32_bf16(afr, bfr, acc[mt], 0, 0, 0);
        }
    }

    int j = n0 + lm;
#pragma unroll
    for (int mt = 0; mt < 8; ++mt) {
#pragma unroll
        for (int r = 0; r < 4; ++r) {
            int m = mt * 16 + kq * 4 + r;
            atomicAdd(&hidden[m * HID + j], acc[mt][r]);
        }
    }
}

// ---------------------------------------------------------------------------
// K4: FC2 + FC3 (fp32 VALU). d_out fp32: [0,8192)=out1, [8192,8448)=out.
// ---------------------------------------------------------------------------
__global__ __launch_bounds__(256) void fc2_kernel(
    const float* __restrict__ hidden,
    const float* __restrict__ W2, const float* __restrict__ b2,
    const float* __restrict__ W3, const float* __restrict__ b3,
    float* __restrict__ out)
{
    int tid = threadIdx.x;
    int c = tid & 63;
    int m = blockIdx.x * 4 + (tid >> 6);
    const float* hrow = hidden + m * HID;
    const float* wrow = W2 + c * HID;

    float acc = b2[c];
    for (int p = 0; p < HID; p += 4) {
        float4 wv = *(const float4*)(wrow + p);
        float4 hv = *(const float4*)(hrow + p);
        acc += hv.x * wv.x + hv.y * wv.y + hv.z * wv.z + hv.w * wv.w;
    }
    out[m * 64 + c] = acc;

    float t0 = acc * W3[c];
    float t1 = acc * W3[64 + c];
#pragma unroll
    for (int off = 32; off > 0; off >>= 1) {
        t0 += __shfl_down(t0, off, 64);
        t1 += __shfl_down(t1, off, 64);
    }
    if (c == 0) {
        float2 pk;
        pk.x = t0 + b3[0];
        pk.y = t1 + b3[1];
        *(float2*)(out + 8192 + m * 2) = pk;
    }
}

// ---------------------------------------------------------------------------
extern "C" void kernel_launch(void* const* d_in, const int* in_sizes, int n_in,
                              void* d_out, int out_size, void* d_ws, size_t ws_size,
                              hipStream_t stream) {
    const float* x  = (const float*)d_in[0];
    const float* Wq = (const float*)d_in[1];
    const float* bq = (const float*)d_in[2];
    const float* Wk = (const float*)d_in[3];
    const float* bk = (const float*)d_in[4];
    const float* Wv = (const float*)d_in[5];
    const float* bv = (const float*)d_in[6];
    const float* Wo = (const float*)d_in[7];
    const float* bo = (const float*)d_in[8];
    const float* W1 = (const float*)d_in[9];
    const float* b1 = (const float*)d_in[10];
    const float* W2 = (const float*)d_in[11];
    const float* b2 = (const float*)d_in[12];
    const float* W3 = (const float*)d_in[13];
    const float* b3 = (const float*)d_in[14];
    float* out = (float*)d_out;

    // ws layout (bytes), total 8,716,288:
    //   [0,         4,096,000)  avbf bf16 [64000][32]
    //   [4,096,000, 8,192,000)  flat bf16 [128][16000]
    //   [8,192,000, 8,716,288)  hidden fp32 [128][1024]
    u16*   avbf   = (u16*)d_ws;
    u16*   flat   = (u16*)((char*)d_ws + 4096000);
    float* hidden = (float*)((char*)d_ws + 8192000);

    attn_fused_mfma<<<dim3(1024), dim3(256), 0, stream>>>(
        x, Wq, bq, Wk, bk, Wv, bv, avbf);
    proj_mfma <<<dim3(1000), dim3(256), 0, stream>>>(avbf, Wo, bo, b1, flat, hidden);
    fc1_mfma  <<<dim3(400),  dim3(256), 0, stream>>>(flat, W1, hidden);
    fc2_kernel<<<dim3(32),   dim3(256), 0, stream>>>(hidden, W2, b2, W3, b3, out);
}